// Round 4
// baseline (801.537 us; speedup 1.0000x reference)
//
#include <hip/hip_runtime.h>

#define B_  8
#define S_  1024
#define D_  768
#define H_  12
#define DK_ 64
#define BH_ 96

typedef _Float16 f16;
typedef _Float16 f16x8 __attribute__((ext_vector_type(8)));
typedef _Float16 f16x4 __attribute__((ext_vector_type(4)));
typedef float    f32x4 __attribute__((ext_vector_type(4)));

#define MFMA16(a, b, c) __builtin_amdgcn_mfma_f32_16x16x32_f16((a), (b), (c), 0, 0, 0)

// ---- LDS swizzle helpers: XOR bits 4..6 of byte offset with f(row) ---------
__device__ __forceinline__ int swz(int row) { return ((row ^ (row >> 3)) & 7) << 4; }

__device__ __forceinline__ f16x8 lds_read8(const f16* base, int row, int rowbytes, int colbyte) {
    const char* p = (const char*)base + row * rowbytes + (colbyte ^ swz(row));
    return *(const f16x8*)p;
}
__device__ __forceinline__ void lds_write8(f16* base, int row, int rowbytes, int colbyte, f16x8 v) {
    char* p = (char*)base + row * rowbytes + (colbyte ^ swz(row));
    *(f16x8*)p = v;
}
__device__ __forceinline__ void lds_write4(f16* base, int row, int rowbytes, int colbyte, f16x4 v) {
    char* p = (char*)base + row * rowbytes + (colbyte ^ swz(row));
    *(f16x4*)p = v;
}
__device__ __forceinline__ void lds_write1(f16* base, int row, int rowbytes, int colbyte, f16 v) {
    char* p = (char*)base + row * rowbytes + (colbyte ^ swz(row));
    *(f16*)p = v;
}
__device__ __forceinline__ f16 lds_read1(const f16* base, int row, int rowbytes, int colbyte) {
    const char* p = (const char*)base + row * rowbytes + (colbyte ^ swz(row));
    return *(const f16*)p;
}

// ---------------------------------------------------------------------------
// Prep A: x fp32 -> f16
// ---------------------------------------------------------------------------
__global__ __launch_bounds__(256) void cvt_x(const float* __restrict__ in,
                                             f16* __restrict__ out, int n4)
{
    const int i = blockIdx.x * 256 + threadIdx.x;
    if (i < n4) {
        const float4 v = ((const float4*)in)[i];
        f16x4 h; h[0] = (f16)v.x; h[1] = (f16)v.y; h[2] = (f16)v.z; h[3] = (f16)v.w;
        ((f16x4*)out)[i] = h;
    }
}

// ---------------------------------------------------------------------------
// Prep B: W [k][n] fp32 -> WT [n][k] f16
// ---------------------------------------------------------------------------
__global__ __launch_bounds__(256) void wT_cvt(
    const float* __restrict__ Wq, const float* __restrict__ Wk,
    const float* __restrict__ Wv, const float* __restrict__ Wo,
    f16* __restrict__ Tq, f16* __restrict__ Tk,
    f16* __restrict__ Tv, f16* __restrict__ To)
{
    const float* W; f16* T;
    if      (blockIdx.z == 0) { W = Wq; T = Tq; }
    else if (blockIdx.z == 1) { W = Wk; T = Tk; }
    else if (blockIdx.z == 2) { W = Wv; T = Tv; }
    else                      { W = Wo; T = To; }

    const int r0 = blockIdx.x * 32;   // k
    const int c0 = blockIdx.y * 32;   // n
    const int t = threadIdx.x, tx = t & 31, ty = t >> 5;

    __shared__ float tile[32][33];
    #pragma unroll
    for (int i = 0; i < 4; ++i)
        tile[ty + 8 * i][tx] = W[(size_t)(r0 + ty + 8 * i) * D_ + c0 + tx];
    __syncthreads();
    #pragma unroll
    for (int i = 0; i < 4; ++i)
        T[(size_t)(c0 + ty + 8 * i) * D_ + r0 + tx] = (f16)tile[tx][ty + 8 * i];
}

// ---------------------------------------------------------------------------
// Pass 1: QKV projection, f16 MFMA. Q is pre-scaled by 0.125 (1/sqrt(DK)).
// ---------------------------------------------------------------------------
__global__ __launch_bounds__(256) void qkv_mfma(
    const f16* __restrict__ x16,
    const f16* __restrict__ Tq, const f16* __restrict__ Tk, const f16* __restrict__ Tv,
    const float* __restrict__ bq, const float* __restrict__ bk, const float* __restrict__ bv,
    f16* __restrict__ qo, f16* __restrict__ ko, f16* __restrict__ vo)
{
    const f16* WT; const float* bias; f16* out; float scale;
    if      (blockIdx.z == 0) { WT = Tq; bias = bq; out = qo; scale = 0.125f; }
    else if (blockIdx.z == 1) { WT = Tk; bias = bk; out = ko; scale = 1.0f; }
    else                      { WT = Tv; bias = bv; out = vo; scale = 1.0f; }

    const int row0 = blockIdx.x * 128;
    const int col0 = blockIdx.y * 128;
    const int t = threadIdx.x, l = t & 63, w = t >> 6;
    const int wr = w >> 1, wc = w & 1;

    __shared__ __attribute__((aligned(16))) f16 As[128 * 64];
    __shared__ __attribute__((aligned(16))) f16 Bs[128 * 64];

    f32x4 acc[4][4] = {};

    for (int kt = 0; kt < D_; kt += 64) {
        __syncthreads();
        #pragma unroll
        for (int ii = 0; ii < 4; ++ii) {
            const int idx = t + ii * 256;
            const int r = idx >> 3, c8 = idx & 7;
            f16x8 v = *(const f16x8*)(x16 + (size_t)(row0 + r) * D_ + kt + c8 * 8);
            lds_write8(As, r, 128, c8 * 16, v);
        }
        #pragma unroll
        for (int ii = 0; ii < 4; ++ii) {
            const int idx = t + ii * 256;
            const int r = idx >> 3, c8 = idx & 7;
            f16x8 v = *(const f16x8*)(WT + (size_t)(col0 + r) * D_ + kt + c8 * 8);
            lds_write8(Bs, r, 128, c8 * 16, v);
        }
        __syncthreads();
        #pragma unroll
        for (int ks = 0; ks < 2; ++ks) {
            f16x8 af[4], bf[4];
            #pragma unroll
            for (int mi = 0; mi < 4; ++mi)
                af[mi] = lds_read8(As, wr * 64 + mi * 16 + (l & 15), 128, ks * 64 + (l >> 4) * 16);
            #pragma unroll
            for (int ni = 0; ni < 4; ++ni)
                bf[ni] = lds_read8(Bs, wc * 64 + ni * 16 + (l & 15), 128, ks * 64 + (l >> 4) * 16);
            #pragma unroll
            for (int mi = 0; mi < 4; ++mi)
                #pragma unroll
                for (int ni = 0; ni < 4; ++ni)
                    acc[mi][ni] = MFMA16(af[mi], bf[ni], acc[mi][ni]);
        }
    }

    #pragma unroll
    for (int mi = 0; mi < 4; ++mi)
        #pragma unroll
        for (int q = 0; q < 4; ++q) {
            const int row = row0 + wr * 64 + mi * 16 + (l >> 4) * 4 + q;
            const int b = row >> 10, s = row & 1023;
            #pragma unroll
            for (int ni = 0; ni < 4; ++ni) {
                const int col = col0 + wc * 64 + ni * 16 + (l & 15);
                const int h = col >> 6, dk = col & 63;
                out[(((size_t)(b * H_ + h)) * S_ + s) * DK_ + dk] = (f16)((acc[mi][ni][q] + bias[col]) * scale);
            }
        }
}

// ---------------------------------------------------------------------------
// Prep C: V [bh][s][64] -> Vt [bh][64][1024]
// ---------------------------------------------------------------------------
__global__ __launch_bounds__(256) void vT_cvt(const f16* __restrict__ V, f16* __restrict__ Vt)
{
    const int bh = blockIdx.x;
    const int s0 = blockIdx.y * 64;
    const int t = threadIdx.x;
    __shared__ __attribute__((aligned(16))) f16 tile[64 * 64];
    #pragma unroll
    for (int ii = 0; ii < 2; ++ii) {
        const int u = t + ii * 256;
        const int r = u >> 3, c8 = u & 7;
        f16x8 v = *(const f16x8*)(V + ((size_t)bh * S_ + s0 + r) * DK_ + c8 * 8);
        lds_write8(tile, r, 128, c8 * 16, v);
    }
    __syncthreads();
    #pragma unroll
    for (int ii = 0; ii < 2; ++ii) {
        const int u = t + ii * 256;
        const int d = u >> 3, sc = u & 7;
        f16x8 o;
        #pragma unroll
        for (int e = 0; e < 8; ++e) o[e] = lds_read1(tile, sc * 8 + e, 128, d * 2);
        *(f16x8*)(Vt + ((size_t)bh * DK_ + d) * S_ + s0 + sc * 8) = o;
    }
}

// ---------------------------------------------------------------------------
// Pass 2: S2[bh][j][k] = Qs[bh,j,:] . pb[j,k,:]; also emits pbT16[j][d][k].
// grid (1024 j, 4 n-tiles of 256).
// ---------------------------------------------------------------------------
__global__ __launch_bounds__(256) void s2_gemm(
    const f16* __restrict__ Qb, const float* __restrict__ pb,
    f16* __restrict__ S2, f16* __restrict__ pbT)
{
    const int j  = blockIdx.x;
    const int n0 = blockIdx.y * 256;
    const int t = threadIdx.x, l = t & 63, w = t >> 6;

    __shared__ __attribute__((aligned(16))) f16 Ps[256 * 64];

    for (int idx = t; idx < 256 * 16; idx += 256) {
        const int r = idx >> 4, c4 = idx & 15;
        const float4 v = *(const float4*)(pb + ((size_t)j * S_ + n0 + r) * DK_ + c4 * 4);
        f16x4 h; h[0] = (f16)v.x; h[1] = (f16)v.y; h[2] = (f16)v.z; h[3] = (f16)v.w;
        lds_write4(Ps, r, 128, c4 * 8, h);
    }

    // Q fragments direct from global (m = bh), K-dim = d (64 = 2 ks steps)
    f16x8 qf[6][2];
    #pragma unroll
    for (int mi = 0; mi < 6; ++mi)
        #pragma unroll
        for (int ks = 0; ks < 2; ++ks)
            qf[mi][ks] = *(const f16x8*)(Qb + ((size_t)(mi * 16 + (l & 15)) * S_ + j) * DK_ + ks * 32 + (l >> 4) * 8);

    __syncthreads();

    f32x4 acc[6][4] = {};
    #pragma unroll
    for (int s = 0; s < 4; ++s) {
        const int nrow = w * 64 + s * 16 + (l & 15);
        const f16x8 b0 = lds_read8(Ps, nrow, 128, (l >> 4) * 16);
        const f16x8 b1 = lds_read8(Ps, nrow, 128, 64 + (l >> 4) * 16);
        #pragma unroll
        for (int mi = 0; mi < 6; ++mi) {
            acc[mi][s] = MFMA16(qf[mi][0], b0, acc[mi][s]);
            acc[mi][s] = MFMA16(qf[mi][1], b1, acc[mi][s]);
        }
    }

    #pragma unroll
    for (int mi = 0; mi < 6; ++mi)
        #pragma unroll
        for (int q = 0; q < 4; ++q) {
            const int bh = mi * 16 + (l >> 4) * 4 + q;
            const size_t base = (size_t)bh * (S_ * S_) + (size_t)j * S_;
            #pragma unroll
            for (int s = 0; s < 4; ++s) {
                const int k = n0 + w * 64 + s * 16 + (l & 15);
                S2[base + k] = (f16)acc[mi][s][q];
            }
        }

    // emit pbT16[j][d][n0:n0+256] from the staged tile
    #pragma unroll
    for (int ii = 0; ii < 8; ++ii) {
        const int u = t + ii * 256;          // d = u>>5 (0..63), kc = u&31
        const int d = u >> 5, kc = u & 31;
        f16x8 o;
        #pragma unroll
        for (int e = 0; e < 8; ++e) o[e] = lds_read1(Ps, kc * 8 + e, 128, d * 2);
        *(f16x8*)(pbT + ((size_t)j * DK_ + d) * S_ + n0 + kc * 8) = o;
    }
}

// ---------------------------------------------------------------------------
// Pass 3 (fused): scores = QsK^T + S2 + mask; softmax; A -> (LDS + global);
// O1 = A @ V via Vt direct-global B-frags -> omid fp32.
// grid (64 j-tiles, 96 bh).
// ---------------------------------------------------------------------------
__global__ __launch_bounds__(256) void attn_av(
    const f16* __restrict__ Qb, const f16* __restrict__ Kb, const f16* __restrict__ Vt,
    const float* __restrict__ vmask, f16* __restrict__ S2A, float* __restrict__ omid)
{
    const int j0 = blockIdx.x * 16;
    const int bh = blockIdx.y, b = bh / H_, h = bh % H_;
    const int t = threadIdx.x, l = t & 63, w = t >> 6;

    __shared__ __attribute__((aligned(16))) f16 Ks[128 * 64];   // 16 KB
    __shared__ __attribute__((aligned(16))) f16 SA[16 * 1024];  // 32 KB: S2, then A
    __shared__ f16 mflag[1024];                                 // 2 KB: 1-vmask
    __shared__ float redm[4][16], reds[4][16];

    for (int idx = t; idx < 16 * 128; idx += 256) {
        const int r = idx >> 7, c8 = idx & 127;
        f16x8 v = *(const f16x8*)(S2A + (size_t)bh * (S_ * S_) + (size_t)(j0 + r) * S_ + c8 * 8);
        lds_write8(SA, r, 2048, c8 * 16, v);
    }
    for (int k = t; k < 1024; k += 256)
        mflag[k] = (f16)(1.0f - vmask[(size_t)b * S_ + k]);

    const f16x8 aq0 = *(const f16x8*)(Qb + ((size_t)bh * S_ + j0 + (l & 15)) * DK_ + (l >> 4) * 8);
    const f16x8 aq1 = *(const f16x8*)(Qb + ((size_t)bh * S_ + j0 + (l & 15)) * DK_ + 32 + (l >> 4) * 8);

    f32x4 acc[16] = {};
    #pragma unroll
    for (int c = 0; c < 8; ++c) {
        __syncthreads();
        for (int idx = t; idx < 128 * 8; idx += 256) {
            const int r = idx >> 3, c8 = idx & 7;
            f16x8 v = *(const f16x8*)(Kb + ((size_t)bh * S_ + c * 128 + r) * DK_ + c8 * 8);
            lds_write8(Ks, r, 128, c8 * 16, v);
        }
        __syncthreads();
        #pragma unroll
        for (int s = 0; s < 2; ++s) {
            const int krow = w * 32 + s * 16 + (l & 15);
            const f16x8 b0 = lds_read8(Ks, krow, 128, (l >> 4) * 16);
            const f16x8 b1 = lds_read8(Ks, krow, 128, 64 + (l >> 4) * 16);
            acc[c * 2 + s] = MFMA16(aq0, b0, acc[c * 2 + s]);
            acc[c * 2 + s] = MFMA16(aq1, b1, acc[c * 2 + s]);
        }
    }

    // combine QK + S2 + mask; per-row max (scale already folded into Q)
    float mrow[4] = {-3e38f, -3e38f, -3e38f, -3e38f};
    #pragma unroll
    for (int f = 0; f < 16; ++f) {
        const int k = (f >> 1) * 128 + w * 32 + (f & 1) * 16 + (l & 15);
        const float vm = (float)mflag[k] * -30000.0f;
        #pragma unroll
        for (int q = 0; q < 4; ++q) {
            const int r = (l >> 4) * 4 + q;
            const float s2v = (float)lds_read1(SA, r, 2048, k * 2);
            const float val = acc[f][q] + s2v + vm;
            acc[f][q] = val;
            mrow[q] = fmaxf(mrow[q], val);
        }
    }
    #pragma unroll
    for (int q = 0; q < 4; ++q) {
        float m = mrow[q];
        #pragma unroll
        for (int off = 1; off < 16; off <<= 1) m = fmaxf(m, __shfl_xor(m, off));
        mrow[q] = m;
    }
    if ((l & 15) == 0) {
        #pragma unroll
        for (int q = 0; q < 4; ++q) redm[w][(l >> 4) * 4 + q] = mrow[q];
    }
    __syncthreads();
    #pragma unroll
    for (int q = 0; q < 4; ++q) {
        const int r = (l >> 4) * 4 + q;
        mrow[q] = fmaxf(fmaxf(redm[0][r], redm[1][r]), fmaxf(redm[2][r], redm[3][r]));
    }

    float lsum[4] = {0.f, 0.f, 0.f, 0.f};
    #pragma unroll
    for (int f = 0; f < 16; ++f)
        #pragma unroll
        for (int q = 0; q < 4; ++q) {
            const float e = __expf(acc[f][q] - mrow[q]);
            acc[f][q] = e;
            lsum[q] += e;
        }
    #pragma unroll
    for (int q = 0; q < 4; ++q) {
        float s = lsum[q];
        #pragma unroll
        for (int off = 1; off < 16; off <<= 1) s += __shfl_xor(s, off);
        lsum[q] = s;
    }
    if ((l & 15) == 0) {
        #pragma unroll
        for (int q = 0; q < 4; ++q) reds[w][(l >> 4) * 4 + q] = lsum[q];
    }
    __syncthreads();
    #pragma unroll
    for (int q = 0; q < 4; ++q) {
        const int r = (l >> 4) * 4 + q;
        lsum[q] = 1.0f / (reds[0][r] + reds[1][r] + reds[2][r] + reds[3][r]);
    }

    // normalized A -> LDS (overwrites SA; all SA reads completed before the
    // redm __syncthreads) and -> global (for apb)
    #pragma unroll
    for (int q = 0; q < 4; ++q) {
        const int r = (l >> 4) * 4 + q;
        const size_t gbase = (size_t)bh * (S_ * S_) + (size_t)(j0 + r) * S_;
        #pragma unroll
        for (int f = 0; f < 16; ++f) {
            const int k = (f >> 1) * 128 + w * 32 + (f & 1) * 16 + (l & 15);
            const f16 a = (f16)(acc[f][q] * lsum[q]);
            S2A[gbase + k] = a;
            lds_write1(SA, r, 2048, k * 2, a);
        }
    }
    __syncthreads();

    // AV: wave w owns d in [w*16, w*16+16); B-frags direct from Vt (L2)
    f32x4 oacc = {};
    const f16* vbase = Vt + ((size_t)bh * DK_ + w * 16 + (l & 15)) * S_ + (l >> 4) * 8;
    #pragma unroll 4
    for (int ks = 0; ks < 32; ++ks) {
        const f16x8 af = lds_read8(SA, l & 15, 2048, ks * 64 + (l >> 4) * 16);
        const f16x8 vf = *(const f16x8*)(vbase + ks * 32);
        oacc = MFMA16(af, vf, oacc);
    }
    #pragma unroll
    for (int q = 0; q < 4; ++q) {
        const int j = j0 + (l >> 4) * 4 + q;
        const int d = w * 16 + (l & 15);
        omid[((size_t)b * S_ + j) * D_ + h * DK_ + d] = oacc[q];
    }
}

// ---------------------------------------------------------------------------
// Pass 4: O2 = A_j @ pbT[j]^T; omid16 = f16(omid + O2). LDS-free, direct frags.
// grid (1024 j).
// ---------------------------------------------------------------------------
__global__ __launch_bounds__(256) void apb_gemm(
    const f16* __restrict__ A, const f16* __restrict__ pbT,
    const float* __restrict__ omid, f16* __restrict__ omid16)
{
    const int j = blockIdx.x;
    const int t = threadIdx.x, l = t & 63, w = t >> 6;

    const f16* abase = A + (size_t)(l & 15) * (S_ * S_) + (size_t)j * S_ + (l >> 4) * 8;
    const f16* bbase = pbT + ((size_t)j * DK_ + w * 16 + (l & 15)) * S_ + (l >> 4) * 8;

    f32x4 acc[6] = {};
    #pragma unroll 4
    for (int ks = 0; ks < 32; ++ks) {
        const f16x8 bf = *(const f16x8*)(bbase + ks * 32);
        #pragma unroll
        for (int mi = 0; mi < 6; ++mi) {
            const f16x8 af = *(const f16x8*)(abase + (size_t)(mi * 16) * (S_ * S_) + ks * 32);
            acc[mi] = MFMA16(af, bf, acc[mi]);
        }
    }

    #pragma unroll
    for (int mi = 0; mi < 6; ++mi)
        #pragma unroll
        for (int q = 0; q < 4; ++q) {
            const int bh = mi * 16 + (l >> 4) * 4 + q;
            const int b = bh / H_, h = bh % H_;
            const int d = w * 16 + (l & 15);
            const size_t o = ((size_t)b * S_ + j) * D_ + h * DK_ + d;
            omid16[o] = (f16)(omid[o] + acc[mi][q]);
        }
}

// ---------------------------------------------------------------------------
// Pass 5: out = (omid16 @ WoT^T + bo) * q_mask
// ---------------------------------------------------------------------------
__global__ __launch_bounds__(256) void out_mfma(
    const f16* __restrict__ a16, const f16* __restrict__ WT,
    const float* __restrict__ bias, const float* __restrict__ qm,
    float* __restrict__ out)
{
    const int row0 = blockIdx.x * 128;
    const int col0 = blockIdx.y * 128;
    const int t = threadIdx.x, l = t & 63, w = t >> 6;
    const int wr = w >> 1, wc = w & 1;

    __shared__ __attribute__((aligned(16))) f16 As[128 * 64];
    __shared__ __attribute__((aligned(16))) f16 Bs[128 * 64];

    f32x4 acc[4][4] = {};

    for (int kt = 0; kt < D_; kt += 64) {
        __syncthreads();
        #pragma unroll
        for (int ii = 0; ii < 4; ++ii) {
            const int idx = t + ii * 256;
            const int r = idx >> 3, c8 = idx & 7;
            f16x8 v = *(const f16x8*)(a16 + (size_t)(row0 + r) * D_ + kt + c8 * 8);
            lds_write8(As, r, 128, c8 * 16, v);
        }
        #pragma unroll
        for (int ii = 0; ii < 4; ++ii) {
            const int idx = t + ii * 256;
            const int r = idx >> 3, c8 = idx & 7;
            f16x8 v = *(const f16x8*)(WT + (size_t)(col0 + r) * D_ + kt + c8 * 8);
            lds_write8(Bs, r, 128, c8 * 16, v);
        }
        __syncthreads();
        #pragma unroll
        for (int ks = 0; ks < 2; ++ks) {
            f16x8 af[4], bf[4];
            #pragma unroll
            for (int mi = 0; mi < 4; ++mi)
                af[mi] = lds_read8(As, wr * 64 + mi * 16 + (l & 15), 128, ks * 64 + (l >> 4) * 16);
            #pragma unroll
            for (int ni = 0; ni < 4; ++ni)
                bf[ni] = lds_read8(Bs, wc * 64 + ni * 16 + (l & 15), 128, ks * 64 + (l >> 4) * 16);
            #pragma unroll
            for (int mi = 0; mi < 4; ++mi)
                #pragma unroll
                for (int ni = 0; ni < 4; ++ni)
                    acc[mi][ni] = MFMA16(af[mi], bf[ni], acc[mi][ni]);
        }
    }

    #pragma unroll
    for (int mi = 0; mi < 4; ++mi)
        #pragma unroll
        for (int q = 0; q < 4; ++q) {
            const int row = row0 + wr * 64 + mi * 16 + (l >> 4) * 4 + q;
            const float qmv = qm[row];
            #pragma unroll
            for (int ni = 0; ni < 4; ++ni) {
                const int col = col0 + wc * 64 + ni * 16 + (l & 15);
                out[(size_t)row * D_ + col] = (acc[mi][ni][q] + bias[col]) * qmv;
            }
        }
}

extern "C" void kernel_launch(void* const* d_in, const int* in_sizes, int n_in,
                              void* d_out, int out_size, void* d_ws, size_t ws_size,
                              hipStream_t stream) {
    const float* x  = (const float*)d_in[0];
    const float* Wq = (const float*)d_in[1];
    const float* bq = (const float*)d_in[2];
    const float* Wk = (const float*)d_in[3];
    const float* bk = (const float*)d_in[4];
    const float* Wv = (const float*)d_in[5];
    const float* bv = (const float*)d_in[6];
    const float* Wo = (const float*)d_in[7];
    const float* bo = (const float*)d_in[8];
    const float* pb = (const float*)d_in[9];
    const float* qm = (const float*)d_in[10];
    const float* vm = (const float*)d_in[11];
    float* out = (float*)d_out;

    const size_t NQ = (size_t)BH_ * S_ * DK_;          // 6,291,456 halfs
    const size_t NW = (size_t)D_ * D_;
    f16* qb  = (f16*)d_ws;
    f16* kb  = qb + NQ;
    f16* vb  = kb + NQ;
    f16* vt  = vb + NQ;
    f16* s2  = vt + NQ;                                 // 96*1024*1024 halfs (201 MB)
    f16* pbT = s2 + (size_t)BH_ * S_ * S_;              // 1024*64*1024 halfs (134 MB)
    f16* x16 = pbT + (size_t)S_ * DK_ * S_;
    f16* tq  = x16 + (size_t)B_ * S_ * D_;
    f16* tk  = tq + NW;
    f16* tv  = tk + NW;
    f16* to  = tv + NW;
    f16* omid16 = to + NW;
    float* omid = (float*)(omid16 + (size_t)B_ * S_ * D_);

    cvt_x<<<dim3((B_ * S_ * D_ / 4 + 255) / 256), 256, 0, stream>>>(x, x16, B_ * S_ * D_ / 4);
    wT_cvt<<<dim3(24, 24, 4), 256, 0, stream>>>(Wq, Wk, Wv, Wo, tq, tk, tv, to);

    qkv_mfma<<<dim3(64, 6, 3), 256, 0, stream>>>(x16, tq, tk, tv, bq, bk, bv, qb, kb, vb);
    vT_cvt<<<dim3(96, 16), 256, 0, stream>>>(vb, vt);

    s2_gemm <<<dim3(1024, 4), 256, 0, stream>>>(qb, pb, s2, pbT);
    attn_av <<<dim3(64, 96),  256, 0, stream>>>(qb, kb, vt, vm, s2, omid);
    apb_gemm<<<dim3(1024),    256, 0, stream>>>(s2, pbT, omid, omid16);

    out_mfma<<<dim3(64, 6), 256, 0, stream>>>(omid16, to, bo, qm, out);
}

// Round 6
// 693.993 us; speedup vs baseline: 1.1550x; 1.1550x over previous
//
#include <hip/hip_runtime.h>

#define B_  8
#define S_  1024
#define D_  768
#define H_  12
#define DK_ 64
#define BH_ 96

typedef _Float16 f16;
typedef _Float16 f16x8 __attribute__((ext_vector_type(8)));
typedef _Float16 f16x4 __attribute__((ext_vector_type(4)));
typedef float    f32x4 __attribute__((ext_vector_type(4)));

#define MFMA16(a, b, c) __builtin_amdgcn_mfma_f32_16x16x32_f16((a), (b), (c), 0, 0, 0)

// ---- LDS swizzle helpers ---------------------------------------------------
__device__ __forceinline__ int swz(int row) { return ((row ^ (row >> 3)) & 7) << 4; }

__device__ __forceinline__ f16x8 lds_read8(const f16* base, int row, int rowbytes, int colbyte) {
    const char* p = (const char*)base + row * rowbytes + (colbyte ^ swz(row));
    return *(const f16x8*)p;
}
__device__ __forceinline__ void lds_write8(f16* base, int row, int rowbytes, int colbyte, f16x8 v) {
    char* p = (char*)base + row * rowbytes + (colbyte ^ swz(row));
    *(f16x8*)p = v;
}
__device__ __forceinline__ void lds_write4(f16* base, int row, int rowbytes, int colbyte, f16x4 v) {
    char* p = (char*)base + row * rowbytes + (colbyte ^ swz(row));
    *(f16x4*)p = v;
}
__device__ __forceinline__ void lds_write1(f16* base, int row, int rowbytes, int colbyte, f16 v) {
    char* p = (char*)base + row * rowbytes + (colbyte ^ swz(row));
    *(f16*)p = v;
}
__device__ __forceinline__ f16 lds_read1(const f16* base, int row, int rowbytes, int colbyte) {
    const char* p = (const char*)base + row * rowbytes + (colbyte ^ swz(row));
    return *(const f16*)p;
}

// ---------------------------------------------------------------------------
// Prep A: x fp32 -> f16
// ---------------------------------------------------------------------------
__global__ __launch_bounds__(256) void cvt_x(const float* __restrict__ in,
                                             f16* __restrict__ out, int n4)
{
    const int i = blockIdx.x * 256 + threadIdx.x;
    if (i < n4) {
        const float4 v = ((const float4*)in)[i];
        f16x4 h; h[0] = (f16)v.x; h[1] = (f16)v.y; h[2] = (f16)v.z; h[3] = (f16)v.w;
        ((f16x4*)out)[i] = h;
    }
}

// ---------------------------------------------------------------------------
// Prep B: W [k][n] fp32 -> WT [n][k] f16
// ---------------------------------------------------------------------------
__global__ __launch_bounds__(256) void wT_cvt(
    const float* __restrict__ Wq, const float* __restrict__ Wk,
    const float* __restrict__ Wv, const float* __restrict__ Wo,
    f16* __restrict__ Tq, f16* __restrict__ Tk,
    f16* __restrict__ Tv, f16* __restrict__ To)
{
    const float* W; f16* T;
    if      (blockIdx.z == 0) { W = Wq; T = Tq; }
    else if (blockIdx.z == 1) { W = Wk; T = Tk; }
    else if (blockIdx.z == 2) { W = Wv; T = Tv; }
    else                      { W = Wo; T = To; }

    const int r0 = blockIdx.x * 32;
    const int c0 = blockIdx.y * 32;
    const int t = threadIdx.x, tx = t & 31, ty = t >> 5;

    __shared__ float tile[32][33];
    #pragma unroll
    for (int i = 0; i < 4; ++i)
        tile[ty + 8 * i][tx] = W[(size_t)(r0 + ty + 8 * i) * D_ + c0 + tx];
    __syncthreads();
    #pragma unroll
    for (int i = 0; i < 4; ++i)
        T[(size_t)(c0 + ty + 8 * i) * D_ + r0 + tx] = (f16)tile[tx][ty + 8 * i];
}

// ---------------------------------------------------------------------------
// Pass 1: QKV projection, f16 MFMA. Q pre-scaled by 0.125.
// ---------------------------------------------------------------------------
__global__ __launch_bounds__(256) void qkv_mfma(
    const f16* __restrict__ x16,
    const f16* __restrict__ Tq, const f16* __restrict__ Tk, const f16* __restrict__ Tv,
    const float* __restrict__ bq, const float* __restrict__ bk, const float* __restrict__ bv,
    f16* __restrict__ qo, f16* __restrict__ ko, f16* __restrict__ vo)
{
    const f16* WT; const float* bias; f16* out; float scale;
    if      (blockIdx.z == 0) { WT = Tq; bias = bq; out = qo; scale = 0.125f; }
    else if (blockIdx.z == 1) { WT = Tk; bias = bk; out = ko; scale = 1.0f; }
    else                      { WT = Tv; bias = bv; out = vo; scale = 1.0f; }

    const int row0 = blockIdx.x * 128;
    const int col0 = blockIdx.y * 128;
    const int t = threadIdx.x, l = t & 63, w = t >> 6;
    const int wr = w >> 1, wc = w & 1;

    __shared__ __attribute__((aligned(16))) f16 As[128 * 64];
    __shared__ __attribute__((aligned(16))) f16 Bs[128 * 64];

    f32x4 acc[4][4] = {};

    for (int kt = 0; kt < D_; kt += 64) {
        __syncthreads();
        #pragma unroll
        for (int ii = 0; ii < 4; ++ii) {
            const int idx = t + ii * 256;
            const int r = idx >> 3, c8 = idx & 7;
            f16x8 v = *(const f16x8*)(x16 + (size_t)(row0 + r) * D_ + kt + c8 * 8);
            lds_write8(As, r, 128, c8 * 16, v);
        }
        #pragma unroll
        for (int ii = 0; ii < 4; ++ii) {
            const int idx = t + ii * 256;
            const int r = idx >> 3, c8 = idx & 7;
            f16x8 v = *(const f16x8*)(WT + (size_t)(col0 + r) * D_ + kt + c8 * 8);
            lds_write8(Bs, r, 128, c8 * 16, v);
        }
        __syncthreads();
        #pragma unroll
        for (int ks = 0; ks < 2; ++ks) {
            f16x8 af[4], bf[4];
            #pragma unroll
            for (int mi = 0; mi < 4; ++mi)
                af[mi] = lds_read8(As, wr * 64 + mi * 16 + (l & 15), 128, ks * 64 + (l >> 4) * 16);
            #pragma unroll
            for (int ni = 0; ni < 4; ++ni)
                bf[ni] = lds_read8(Bs, wc * 64 + ni * 16 + (l & 15), 128, ks * 64 + (l >> 4) * 16);
            #pragma unroll
            for (int mi = 0; mi < 4; ++mi)
                #pragma unroll
                for (int ni = 0; ni < 4; ++ni)
                    acc[mi][ni] = MFMA16(af[mi], bf[ni], acc[mi][ni]);
        }
    }

    #pragma unroll
    for (int mi = 0; mi < 4; ++mi)
        #pragma unroll
        for (int q = 0; q < 4; ++q) {
            const int row = row0 + wr * 64 + mi * 16 + (l >> 4) * 4 + q;
            const int b = row >> 10, s = row & 1023;
            #pragma unroll
            for (int ni = 0; ni < 4; ++ni) {
                const int col = col0 + wc * 64 + ni * 16 + (l & 15);
                const int h = col >> 6, dk = col & 63;
                out[(((size_t)(b * H_ + h)) * S_ + s) * DK_ + dk] = (f16)((acc[mi][ni][q] + bias[col]) * scale);
            }
        }
}

// ---------------------------------------------------------------------------
// Prep C: V [bh][s][64] -> Vt [bh][64][1024]
// ---------------------------------------------------------------------------
__global__ __launch_bounds__(256) void vT_cvt(const f16* __restrict__ V, f16* __restrict__ Vt)
{
    const int bh = blockIdx.x;
    const int s0 = blockIdx.y * 64;
    const int t = threadIdx.x;
    __shared__ __attribute__((aligned(16))) f16 tile[64 * 64];
    #pragma unroll
    for (int ii = 0; ii < 2; ++ii) {
        const int u = t + ii * 256;
        const int r = u >> 3, c8 = u & 7;
        f16x8 v = *(const f16x8*)(V + ((size_t)bh * S_ + s0 + r) * DK_ + c8 * 8);
        lds_write8(tile, r, 128, c8 * 16, v);
    }
    __syncthreads();
    #pragma unroll
    for (int ii = 0; ii < 2; ++ii) {
        const int u = t + ii * 256;
        const int d = u >> 3, sc = u & 7;
        f16x8 o;
        #pragma unroll
        for (int e = 0; e < 8; ++e) o[e] = lds_read1(tile, sc * 8 + e, 128, d * 2);
        *(f16x8*)(Vt + ((size_t)bh * DK_ + d) * S_ + s0 + sc * 8) = o;
    }
}

// ---------------------------------------------------------------------------
// Pass 2: S2[bh][j][k] = Qs[bh,j,:] . pb[j,k,:]; also emits pbT16[j][d][k].
// ---------------------------------------------------------------------------
__global__ __launch_bounds__(256) void s2_gemm(
    const f16* __restrict__ Qb, const float* __restrict__ pb,
    f16* __restrict__ S2, f16* __restrict__ pbT)
{
    const int j  = blockIdx.x;
    const int n0 = blockIdx.y * 256;
    const int t = threadIdx.x, l = t & 63, w = t >> 6;

    __shared__ __attribute__((aligned(16))) f16 Ps[256 * 64];

    for (int idx = t; idx < 256 * 16; idx += 256) {
        const int r = idx >> 4, c4 = idx & 15;
        const float4 v = *(const float4*)(pb + ((size_t)j * S_ + n0 + r) * DK_ + c4 * 4);
        f16x4 h; h[0] = (f16)v.x; h[1] = (f16)v.y; h[2] = (f16)v.z; h[3] = (f16)v.w;
        lds_write4(Ps, r, 128, c4 * 8, h);
    }

    f16x8 qf[6][2];
    #pragma unroll
    for (int mi = 0; mi < 6; ++mi)
        #pragma unroll
        for (int ks = 0; ks < 2; ++ks)
            qf[mi][ks] = *(const f16x8*)(Qb + ((size_t)(mi * 16 + (l & 15)) * S_ + j) * DK_ + ks * 32 + (l >> 4) * 8);

    __syncthreads();

    f32x4 acc[6][4] = {};
    #pragma unroll
    for (int s = 0; s < 4; ++s) {
        const int nrow = w * 64 + s * 16 + (l & 15);
        const f16x8 b0 = lds_read8(Ps, nrow, 128, (l >> 4) * 16);
        const f16x8 b1 = lds_read8(Ps, nrow, 128, 64 + (l >> 4) * 16);
        #pragma unroll
        for (int mi = 0; mi < 6; ++mi) {
            acc[mi][s] = MFMA16(qf[mi][0], b0, acc[mi][s]);
            acc[mi][s] = MFMA16(qf[mi][1], b1, acc[mi][s]);
        }
    }

    #pragma unroll
    for (int mi = 0; mi < 6; ++mi)
        #pragma unroll
        for (int q = 0; q < 4; ++q) {
            const int bh = mi * 16 + (l >> 4) * 4 + q;
            const size_t base = (size_t)bh * (S_ * S_) + (size_t)j * S_;
            #pragma unroll
            for (int s = 0; s < 4; ++s) {
                const int k = n0 + w * 64 + s * 16 + (l & 15);
                S2[base + k] = (f16)acc[mi][s][q];
            }
        }

    #pragma unroll
    for (int ii = 0; ii < 8; ++ii) {
        const int u = t + ii * 256;
        const int d = u >> 5, kc = u & 31;
        f16x8 o;
        #pragma unroll
        for (int e = 0; e < 8; ++e) o[e] = lds_read1(Ps, kc * 8 + e, 128, d * 2);
        *(f16x8*)(pbT + ((size_t)j * DK_ + d) * S_ + n0 + kc * 8) = o;
    }
}

// ---------------------------------------------------------------------------
// Pass 3: scores = QsK^T + S2 + mask; softmax; normalized A back to S2A.
// K fragments DIRECT from global (L2-resident slab, no barriers in QK).
// ---------------------------------------------------------------------------
__global__ __launch_bounds__(256) void attn_sm(
    const f16* __restrict__ Qb, const f16* __restrict__ Kb,
    const float* __restrict__ vmask, f16* __restrict__ S2A)
{
    const int j0 = blockIdx.x * 16;
    const int bh = blockIdx.y, b = bh / H_;
    const int t = threadIdx.x, l = t & 63, w = t >> 6;

    __shared__ __attribute__((aligned(16))) f16 SA[16 * 1024];  // 32 KB: S2, then A
    __shared__ f16 mflag[1024];
    __shared__ float redm[4][16], reds[4][16];

    for (int idx = t; idx < 16 * 128; idx += 256) {
        const int r = idx >> 7, c8 = idx & 127;
        f16x8 v = *(const f16x8*)(S2A + (size_t)bh * (S_ * S_) + (size_t)(j0 + r) * S_ + c8 * 8);
        lds_write8(SA, r, 2048, c8 * 16, v);
    }
    for (int k = t; k < 1024; k += 256)
        mflag[k] = (f16)(1.0f - vmask[(size_t)b * S_ + k]);

    const f16x8 aq0 = *(const f16x8*)(Qb + ((size_t)bh * S_ + j0 + (l & 15)) * DK_ + (l >> 4) * 8);
    const f16x8 aq1 = *(const f16x8*)(Qb + ((size_t)bh * S_ + j0 + (l & 15)) * DK_ + 32 + (l >> 4) * 8);
    __syncthreads();

    // QK^T: 32 MFMAs, B-frags direct from global K (no LDS, no barriers)
    f32x4 acc[16] = {};
    #pragma unroll
    for (int f = 0; f < 16; ++f) {
        const int k = (f >> 1) * 128 + w * 32 + (f & 1) * 16 + (l & 15);
        const f16* kp = Kb + ((size_t)bh * S_ + k) * DK_ + (l >> 4) * 8;
        const f16x8 b0 = *(const f16x8*)kp;
        const f16x8 b1 = *(const f16x8*)(kp + 32);
        acc[f] = MFMA16(aq0, b0, acc[f]);
        acc[f] = MFMA16(aq1, b1, acc[f]);
    }

    // combine QK + S2 + mask; per-row max
    float mrow[4] = {-3e38f, -3e38f, -3e38f, -3e38f};
    #pragma unroll
    for (int f = 0; f < 16; ++f) {
        const int k = (f >> 1) * 128 + w * 32 + (f & 1) * 16 + (l & 15);
        const float vm = (float)mflag[k] * -30000.0f;
        #pragma unroll
        for (int q = 0; q < 4; ++q) {
            const int r = (l >> 4) * 4 + q;
            const float s2v = (float)lds_read1(SA, r, 2048, k * 2);
            const float val = acc[f][q] + s2v + vm;
            acc[f][q] = val;
            mrow[q] = fmaxf(mrow[q], val);
        }
    }
    #pragma unroll
    for (int q = 0; q < 4; ++q) {
        float m = mrow[q];
        #pragma unroll
        for (int off = 1; off < 16; off <<= 1) m = fmaxf(m, __shfl_xor(m, off));
        mrow[q] = m;
    }
    if ((l & 15) == 0) {
        #pragma unroll
        for (int q = 0; q < 4; ++q) redm[w][(l >> 4) * 4 + q] = mrow[q];
    }
    __syncthreads();
    #pragma unroll
    for (int q = 0; q < 4; ++q) {
        const int r = (l >> 4) * 4 + q;
        mrow[q] = fmaxf(fmaxf(redm[0][r], redm[1][r]), fmaxf(redm[2][r], redm[3][r]));
    }

    float lsum[4] = {0.f, 0.f, 0.f, 0.f};
    #pragma unroll
    for (int f = 0; f < 16; ++f)
        #pragma unroll
        for (int q = 0; q < 4; ++q) {
            const float e = __expf(acc[f][q] - mrow[q]);
            acc[f][q] = e;
            lsum[q] += e;
        }
    #pragma unroll
    for (int q = 0; q < 4; ++q) {
        float s = lsum[q];
        #pragma unroll
        for (int off = 1; off < 16; off <<= 1) s += __shfl_xor(s, off);
        lsum[q] = s;
    }
    if ((l & 15) == 0) {
        #pragma unroll
        for (int q = 0; q < 4; ++q) reds[w][(l >> 4) * 4 + q] = lsum[q];
    }
    __syncthreads();
    #pragma unroll
    for (int q = 0; q < 4; ++q) {
        const int r = (l >> 4) * 4 + q;
        lsum[q] = 1.0f / (reds[0][r] + reds[1][r] + reds[2][r] + reds[3][r]);
    }

    // normalized A -> SA (same cells this thread read in combine; no hazard)
    #pragma unroll
    for (int q = 0; q < 4; ++q) {
        const int r = (l >> 4) * 4 + q;
        #pragma unroll
        for (int f = 0; f < 16; ++f) {
            const int k = (f >> 1) * 128 + w * 32 + (f & 1) * 16 + (l & 15);
            lds_write1(SA, r, 2048, k * 2, (f16)(acc[f][q] * lsum[q]));
        }
    }
    __syncthreads();

    // vectorized, fully-coalesced copy-out of A
    for (int idx = t; idx < 16 * 128; idx += 256) {
        const int r = idx >> 7, c8 = idx & 127;
        const f16x8 v = lds_read8(SA, r, 2048, c8 * 16);
        *(f16x8*)(S2A + (size_t)bh * (S_ * S_) + (size_t)(j0 + r) * S_ + c8 * 8) = v;
    }
}

// ---------------------------------------------------------------------------
// Pass 4a: O1 = A @ V via Vt, LDS-free, barrier-free. grid (16 j-tiles, 96 bh).
// ---------------------------------------------------------------------------
__global__ __launch_bounds__(256) void av_gemm(
    const f16* __restrict__ A, const f16* __restrict__ Vt,
    float* __restrict__ omid)
{
    const int j0 = blockIdx.x * 64;
    const int bh = blockIdx.y, b = bh / H_, h = bh % H_;
    const int t = threadIdx.x, l = t & 63, w = t >> 6;

    const f16* abase = A + (size_t)bh * (S_ * S_) + (size_t)(j0 + w * 16 + (l & 15)) * S_ + (l >> 4) * 8;
    const f16* vbase = Vt + (size_t)bh * DK_ * S_ + (size_t)(l & 15) * S_ + (l >> 4) * 8;

    f32x4 acc[4] = {};
    #pragma unroll 4
    for (int ks = 0; ks < 32; ++ks) {
        const f16x8 af = *(const f16x8*)(abase + ks * 32);
        #pragma unroll
        for (int ni = 0; ni < 4; ++ni) {
            const f16x8 vf = *(const f16x8*)(vbase + (size_t)(ni * 16) * S_ + ks * 32);
            acc[ni] = MFMA16(af, vf, acc[ni]);
        }
    }

    #pragma unroll
    for (int ni = 0; ni < 4; ++ni)
        #pragma unroll
        for (int q = 0; q < 4; ++q) {
            const int j = j0 + w * 16 + (l >> 4) * 4 + q;
            const int d = ni * 16 + (l & 15);
            omid[((size_t)b * S_ + j) * D_ + h * DK_ + d] = acc[ni][q];
        }
}

// ---------------------------------------------------------------------------
// Pass 4b: O2 = A_j @ pbT[j]^T; omid16 = f16(omid + O2). LDS-free.
// ---------------------------------------------------------------------------
__global__ __launch_bounds__(256) void apb_gemm(
    const f16* __restrict__ A, const f16* __restrict__ pbT,
    const float* __restrict__ omid, f16* __restrict__ omid16)
{
    const int j = blockIdx.x;
    const int t = threadIdx.x, l = t & 63, w = t >> 6;

    const f16* abase = A + (size_t)(l & 15) * (S_ * S_) + (size_t)j * S_ + (l >> 4) * 8;
    const f16* bbase = pbT + ((size_t)j * DK_ + w * 16 + (l & 15)) * S_ + (l >> 4) * 8;

    f32x4 acc[6] = {};
    #pragma unroll 4
    for (int ks = 0; ks < 32; ++ks) {
        const f16x8 bf = *(const f16x8*)(bbase + ks * 32);
        #pragma unroll
        for (int mi = 0; mi < 6; ++mi) {
            const f16x8 af = *(const f16x8*)(abase + (size_t)(mi * 16) * (S_ * S_) + ks * 32);
            acc[mi] = MFMA16(af, bf, acc[mi]);
        }
    }

    #pragma unroll
    for (int mi = 0; mi < 6; ++mi)
        #pragma unroll
        for (int q = 0; q < 4; ++q) {
            const int bh = mi * 16 + (l >> 4) * 4 + q;
            const int b = bh / H_, h = bh % H_;
            const int d = w * 16 + (l & 15);
            const size_t o = ((size_t)b * S_ + j) * D_ + h * DK_ + d;
            omid16[o] = (f16)(omid[o] + acc[mi][q]);
        }
}

// ---------------------------------------------------------------------------
// Pass 5: out = (omid16 @ WoT^T + bo) * q_mask
// ---------------------------------------------------------------------------
__global__ __launch_bounds__(256) void out_mfma(
    const f16* __restrict__ a16, const f16* __restrict__ WT,
    const float* __restrict__ bias, const float* __restrict__ qm,
    float* __restrict__ out)
{
    const int row0 = blockIdx.x * 128;
    const int col0 = blockIdx.y * 128;
    const int t = threadIdx.x, l = t & 63, w = t >> 6;
    const int wr = w >> 1, wc = w & 1;

    __shared__ __attribute__((aligned(16))) f16 As[128 * 64];
    __shared__ __attribute__((aligned(16))) f16 Bs[128 * 64];

    f32x4 acc[4][4] = {};

    for (int kt = 0; kt < D_; kt += 64) {
        __syncthreads();
        #pragma unroll
        for (int ii = 0; ii < 4; ++ii) {
            const int idx = t + ii * 256;
            const int r = idx >> 3, c8 = idx & 7;
            f16x8 v = *(const f16x8*)(a16 + (size_t)(row0 + r) * D_ + kt + c8 * 8);
            lds_write8(As, r, 128, c8 * 16, v);
        }
        #pragma unroll
        for (int ii = 0; ii < 4; ++ii) {
            const int idx = t + ii * 256;
            const int r = idx >> 3, c8 = idx & 7;
            f16x8 v = *(const f16x8*)(WT + (size_t)(col0 + r) * D_ + kt + c8 * 8);
            lds_write8(Bs, r, 128, c8 * 16, v);
        }
        __syncthreads();
        #pragma unroll
        for (int ks = 0; ks < 2; ++ks) {
            f16x8 af[4], bf[4];
            #pragma unroll
            for (int mi = 0; mi < 4; ++mi)
                af[mi] = lds_read8(As, wr * 64 + mi * 16 + (l & 15), 128, ks * 64 + (l >> 4) * 16);
            #pragma unroll
            for (int ni = 0; ni < 4; ++ni)
                bf[ni] = lds_read8(Bs, wc * 64 + ni * 16 + (l & 15), 128, ks * 64 + (l >> 4) * 16);
            #pragma unroll
            for (int mi = 0; mi < 4; ++mi)
                #pragma unroll
                for (int ni = 0; ni < 4; ++ni)
                    acc[mi][ni] = MFMA16(af[mi], bf[ni], acc[mi][ni]);
        }
    }

    #pragma unroll
    for (int mi = 0; mi < 4; ++mi)
        #pragma unroll
        for (int q = 0; q < 4; ++q) {
            const int row = row0 + wr * 64 + mi * 16 + (l >> 4) * 4 + q;
            const float qmv = qm[row];
            #pragma unroll
            for (int ni = 0; ni < 4; ++ni) {
                const int col = col0 + wc * 64 + ni * 16 + (l & 15);
                out[(size_t)row * D_ + col] = (acc[mi][ni][q] + bias[col]) * qmv;
            }
        }
}

extern "C" void kernel_launch(void* const* d_in, const int* in_sizes, int n_in,
                              void* d_out, int out_size, void* d_ws, size_t ws_size,
                              hipStream_t stream) {
    const float* x  = (const float*)d_in[0];
    const float* Wq = (const float*)d_in[1];
    const float* bq = (const float*)d_in[2];
    const float* Wk = (const float*)d_in[3];
    const float* bk = (const float*)d_in[4];
    const float* Wv = (const float*)d_in[5];
    const float* bv = (const float*)d_in[6];
    const float* Wo = (const float*)d_in[7];
    const float* bo = (const float*)d_in[8];
    const float* pb = (const float*)d_in[9];
    const float* qm = (const float*)d_in[10];
    const float* vm = (const float*)d_in[11];
    float* out = (float*)d_out;

    const size_t NQ = (size_t)BH_ * S_ * DK_;
    const size_t NW = (size_t)D_ * D_;
    f16* qb  = (f16*)d_ws;
    f16* kb  = qb + NQ;
    f16* vb  = kb + NQ;
    f16* vt  = vb + NQ;
    f16* s2  = vt + NQ;                                 // 201 MB
    f16* pbT = s2 + (size_t)BH_ * S_ * S_;              // 134 MB
    f16* x16 = pbT + (size_t)S_ * DK_ * S_;
    f16* tq  = x16 + (size_t)B_ * S_ * D_;
    f16* tk  = tq + NW;
    f16* tv  = tk + NW;
    f16* to  = tv + NW;
    f16* omid16 = to + NW;
    float* omid = (float*)(omid16 + (size_t)B_ * S_ * D_);

    cvt_x<<<dim3((B_ * S_ * D_ / 4 + 255) / 256), 256, 0, stream>>>(x, x16, B_ * S_ * D_ / 4);
    wT_cvt<<<dim3(24, 24, 4), 256, 0, stream>>>(Wq, Wk, Wv, Wo, tq, tk, tv, to);

    qkv_mfma<<<dim3(64, 6, 3), 256, 0, stream>>>(x16, tq, tk, tv, bq, bk, bv, qb, kb, vb);
    vT_cvt<<<dim3(96, 16), 256, 0, stream>>>(vb, vt);

    s2_gemm <<<dim3(1024, 4), 256, 0, stream>>>(qb, pb, s2, pbT);
    attn_sm <<<dim3(64, 96),  256, 0, stream>>>(qb, kb, vm, s2);
    av_gemm <<<dim3(16, 96),  256, 0, stream>>>(s2, vt, omid);   // 16*64 = all 1024 j
    apb_gemm<<<dim3(1024),    256, 0, stream>>>(s2, pbT, omid, omid16);

    out_mfma<<<dim3(64, 6), 256, 0, stream>>>(omid16, to, bo, qm, out);
}